// Round 10
// baseline (3069.810 us; speedup 1.0000x reference)
//
#include <hip/hip_runtime.h>
#include <stdint.h>

// Problem constants
#define Bq   128
#define Tq   512
#define Fq   64
#define Hq   512
#define G4q  2048
#define FUTq 64

// 256 WGs = 8 row-groups (mg = wg&7 -> XCD-local gang) x 32 unit-groups
// (ng = wg>>3), 256 thr (4 waves).
// h exchanged as [parity][row][unit] u32 (hi-bf16 | lo-bf16<<16), full 64B
// lines, with a STEP TAG embedded in bit16 (lo-residual LSB) of word0 of
// every 16B chunk: tag(h_t) = (t>>1)&1.  Consumers poll the DATA lines
// directly (load + tag check + retry) -> the successful poll IS the load:
// one MALL RT per step instead of store-ack + flag + load (3 RTs).
// Producer publish is fire-and-forget (no vmcnt, no flag) except at the
// final step (hfin + epilogue flag). U resident in registers as hi/lo bf16
// B-fragments; A-fragments shared across waves via LDS.

typedef __attribute__((ext_vector_type(8))) short bfrag_t;
typedef __attribute__((ext_vector_type(4))) float accf_t;
typedef __attribute__((ext_vector_type(4))) float f4_t;
typedef __attribute__((ext_vector_type(4))) unsigned int u32x4;  // asm-safe 128b payload

static __device__ __forceinline__ accf_t mfma16(uint4 a, uint4 b, accf_t acc) {
  return __builtin_amdgcn_mfma_f32_16x16x32_bf16(
      __builtin_bit_cast(bfrag_t, a), __builtin_bit_cast(bfrag_t, b), acc, 0, 0, 0);
}

static __device__ __forceinline__ void pack2(float f0, float f1, uint32_t& h, uint32_t& l) {
  uint32_t b0 = __float_as_uint(f0), b1 = __float_as_uint(f1);
  h = (b0 >> 16) | (b1 & 0xffff0000u);
  float r0 = f0 - __uint_as_float(b0 & 0xffff0000u);
  float r1 = f1 - __uint_as_float(b1 & 0xffff0000u);
  l = (__float_as_uint(r0) >> 16) | (__float_as_uint(r1) & 0xffff0000u);
}

static __device__ __forceinline__ float sigmoidf_(float v) {
  return __fdividef(1.0f, 1.0f + __expf(-v));
}

// coherence-point 16B ops with compile-time byte offset
#define LD16(dst, base, IMM)                                                \
  asm volatile("global_load_dwordx4 %0, %1, off offset:" IMM " sc0 sc1"     \
               : "=v"(dst) : "v"(base) : "memory")
static __device__ __forceinline__ void st16_cc(void* p, u32x4 v) {
  asm volatile("global_store_dwordx4 %0, %1, off sc0 sc1" :: "v"(p), "v"(v) : "memory");
}
static __device__ __forceinline__ void stf_cc(void* p, float v) {
  asm volatile("global_store_dword %0, %1, off sc0 sc1" :: "v"(p), "v"(v) : "memory");
}
static __device__ __forceinline__ void wait_vm0() {
  asm volatile("s_waitcnt vmcnt(0)" ::: "memory");
  __builtin_amdgcn_sched_barrier(0);
}

static __device__ __forceinline__ void poll1(uint32_t* f, uint32_t tgt) {
  int guard = 0;
  while (__hip_atomic_load(f, __ATOMIC_RELAXED, __HIP_MEMORY_SCOPE_AGENT) < tgt) {
    __builtin_amdgcn_s_sleep(1);
    if (++guard > (1 << 23)) return;  // anti-hang; broken run fails validation
  }
}

__global__ __launch_bounds__(256, 1) void lstm_persist(
    const float* __restrict__ x, const float* __restrict__ W,
    const float* __restrict__ U, const float* __restrict__ bias_v,
    const float* __restrict__ Wd, const float* __restrict__ bd,
    uint32_t* __restrict__ hbuf,          // [2][128][512] u32 (hi | lo<<16, tagged)
    uint32_t* __restrict__ prod,          // [8][32] per-WG flags (final step only)
    float* __restrict__ hfin,             // [128][512] final h fp32
    float* __restrict__ out)
{
  const int wg  = blockIdx.x;
  const int mg  = wg & 7;                 // XCD-local gang (%8 round-robin)
  const int ng  = wg >> 3;
  const int tid = threadIdx.x;
  const int wv  = tid >> 6;
  const int l   = tid & 63;
  const int c   = l & 15;
  const int h4  = l >> 4;
  const int gate = c & 3;
  const int unit = ng * 16 + wv * 4 + (c >> 2);
  const int srccol = gate * 512 + unit;

  __shared__ float lds[128][65];
  __shared__ uint32_t stg[2][16][16];     // [parity][row16][unit16]
  __shared__ uint4 fragH[16 * 64];        // per-K-slice hi A-frags, [j][lane]
  __shared__ uint4 fragL[16 * 64];        // per-K-slice lo A-frags

  // ---------------- stage U into B-fragment registers (hi/lo bf16) ----------
  uint4 Bhi[16], Blo[16];
  const int srow = tid >> 2, sg = tid & 3;
  #pragma unroll
  for (int tb = 0; tb < 4; ++tb) {
    __syncthreads();
    #pragma unroll
    for (int p = 0; p < 2; ++p) {
      const int kl = p * 64 + srow;
      const float* src = U + (size_t)(tb * 128 + kl) * G4q + sg * 512 + ng * 16;
      #pragma unroll
      for (int q = 0; q < 4; ++q) {
        f4_t vv = *(const f4_t*)(src + q * 4);
        #pragma unroll
        for (int e = 0; e < 4; ++e) {
          int uu = q * 4 + e;
          lds[kl][(uu >> 2) * 16 + (uu & 3) * 4 + sg] = vv[e];
        }
      }
    }
    __syncthreads();
    #pragma unroll
    for (int k2 = 0; k2 < 4; ++k2) {
      const int kk = tb * 4 + k2;
      uint32_t wh[4], wl[4];
      #pragma unroll
      for (int jp = 0; jp < 4; ++jp) {
        const int kloc = k2 * 32 + h4 * 8 + jp * 2;
        pack2(lds[kloc][wv * 16 + c], lds[kloc + 1][wv * 16 + c], wh[jp], wl[jp]);
      }
      Bhi[kk] = make_uint4(wh[0], wh[1], wh[2], wh[3]);
      Blo[kk] = make_uint4(wl[0], wl[1], wl[2], wl[3]);
    }
  }

  // ---------------- stage W the same way ------------------------------------
  uint4 Wh[2], Wl[2];
  __syncthreads();
  {
    const float* src = W + (size_t)srow * G4q + sg * 512 + ng * 16;
    #pragma unroll
    for (int q = 0; q < 4; ++q) {
      f4_t vv = *(const f4_t*)(src + q * 4);
      #pragma unroll
      for (int e = 0; e < 4; ++e) {
        int uu = q * 4 + e;
        lds[srow][(uu >> 2) * 16 + (uu & 3) * 4 + sg] = vv[e];
      }
    }
  }
  __syncthreads();
  #pragma unroll
  for (int kk = 0; kk < 2; ++kk) {
    uint32_t wh[4], wl[4];
    #pragma unroll
    for (int jp = 0; jp < 4; ++jp) {
      const int kloc = kk * 32 + h4 * 8 + jp * 2;
      pack2(lds[kloc][wv * 16 + c], lds[kloc + 1][wv * 16 + c], wh[jp], wl[jp]);
    }
    Wh[kk] = make_uint4(wh[0], wh[1], wh[2], wh[3]);
    Wl[kk] = make_uint4(wl[0], wl[1], wl[2], wl[3]);
  }
  __syncthreads();

  const float bval = bias_v[srccol];
  float cst[4] = {0.f, 0.f, 0.f, 0.f};

  const float* xrow = x + (size_t)(mg * 16 + c) * Tq * Fq + h4 * 8;
  const char*  hbb  = (const char*)hbuf;
  const size_t rowoff = (size_t)(mg * 16 + c) * 2048 + h4 * 32;

  // ---------------- recurrence ----------------------------------------------
  for (int t = 0; t < Tq; ++t) {
    const int pb = t & 1;
    const uint32_t tb16 = (((uint32_t)t >> 1) & 1u) << 16;   // expected tag

    // optimistic issue of this wave's 8 h-chunk loads (tag-carrying data)
    const char* hp2 = hbb + (size_t)pb * 262144 + rowoff + wv * 512;
    uint4 q0, q1, q2, q3, q4, q5, q6, q7;
#define LOAD8 do {                                                   \
      LD16(q0, hp2, "0");   LD16(q1, hp2, "16");                     \
      LD16(q2, hp2, "128"); LD16(q3, hp2, "144");                    \
      LD16(q4, hp2, "256"); LD16(q5, hp2, "272");                    \
      LD16(q6, hp2, "384"); LD16(q7, hp2, "400"); } while (0)
    LOAD8;

    // x @ W under the load latency — no h dependency
    accf_t accA = {bval, bval, bval, bval};
    accf_t accB = {0.f, 0.f, 0.f, 0.f};
    accf_t accC = {0.f, 0.f, 0.f, 0.f};
    {
      const float* xp = xrow + (size_t)t * Fq;
      #pragma unroll
      for (int kk = 0; kk < 2; ++kk) {
        f4_t xa = *(const f4_t*)(xp + kk * 32);
        f4_t xb = *(const f4_t*)(xp + kk * 32 + 4);
        uint32_t xh[4], xl[4];
        pack2(xa[0], xa[1], xh[0], xl[0]);
        pack2(xa[2], xa[3], xh[1], xl[1]);
        pack2(xb[0], xb[1], xh[2], xl[2]);
        pack2(xb[2], xb[3], xh[3], xl[3]);
        uint4 XH = make_uint4(xh[0], xh[1], xh[2], xh[3]);
        uint4 XL = make_uint4(xl[0], xl[1], xl[2], xl[3]);
        accA = mfma16(XH, Wh[kk], accA);
        accB = mfma16(XL, Wh[kk], accB);
        accC = mfma16(XH, Wl[kk], accC);
      }
    }

    // tag-check retry loop: successful poll iteration IS the data load
    {
      int guard = 0;
      for (;;) {
        wait_vm0();
        uint32_t mm = ((q0.x ^ tb16) | (q1.x ^ tb16) | (q2.x ^ tb16) |
                       (q3.x ^ tb16) | (q4.x ^ tb16) | (q5.x ^ tb16) |
                       (q6.x ^ tb16) | (q7.x ^ tb16)) & 0x10000u;
        if (!__ballot(mm != 0)) break;
        __builtin_amdgcn_s_sleep(1);
        if (++guard > (1 << 22)) break;   // anti-hang; broken run fails validation
        LOAD8;
      }
    }
#undef LOAD8

    // perm repack + share this wave's 4 K-slices via LDS
    {
      uint4 qs[8] = {q0, q1, q2, q3, q4, q5, q6, q7};
      #pragma unroll
      for (int jj = 0; jj < 4; ++jj) {
        uint4 a = qs[2 * jj], b = qs[2 * jj + 1];
        uint4 ahf, alf;
        ahf.x = __builtin_amdgcn_perm(a.y, a.x, 0x05040100u);
        ahf.y = __builtin_amdgcn_perm(a.w, a.z, 0x05040100u);
        ahf.z = __builtin_amdgcn_perm(b.y, b.x, 0x05040100u);
        ahf.w = __builtin_amdgcn_perm(b.w, b.z, 0x05040100u);
        alf.x = __builtin_amdgcn_perm(a.y, a.x, 0x07060302u);
        alf.y = __builtin_amdgcn_perm(a.w, a.z, 0x07060302u);
        alf.z = __builtin_amdgcn_perm(b.y, b.x, 0x07060302u);
        alf.w = __builtin_amdgcn_perm(b.w, b.z, 0x07060302u);
        fragH[(wv * 4 + jj) * 64 + l] = ahf;
        fragL[(wv * 4 + jj) * 64 + l] = alf;
      }
    }
    __syncthreads();   // barrier C: frags visible to all waves

    // MFMA over all 16 K-slices from LDS
    #pragma unroll
    for (int j = 0; j < 16; ++j) {
      uint4 ah = fragH[j * 64 + l];
      uint4 al = fragL[j * 64 + l];
      accA = mfma16(ah, Bhi[j], accA);
      accB = mfma16(al, Bhi[j], accB);
      accC = mfma16(ah, Blo[j], accC);
    }

    // gates + state update; pack word for (row = h4*4+gate, unit)
    uint32_t word_out = 0;
    #pragma unroll
    for (int r = 0; r < 4; ++r) {
      float zr = accA[r] + accB[r] + accC[r];
      float s1 = __shfl_xor(zr, 1);
      float s2 = __shfl_xor(zr, 2);
      float s3 = __shfl_xor(zr, 3);
      const bool b0 = (gate & 1), b1 = (gate & 2);
      float t01a = b0 ? s1 : zr, t23a = b0 ? s3 : s2;
      float iv = b1 ? t23a : t01a;
      float gv = b1 ? t01a : t23a;
      float t01b = b0 ? zr : s1, t23b = b0 ? s2 : s3;
      float fv = b1 ? t23b : t01b;
      float ov = b1 ? t01b : t23b;
      float si = sigmoidf_(iv);
      float sf = sigmoidf_(fv);
      float so = sigmoidf_(ov);
      float cn = sf * cst[r] + si * fmaxf(gv, 0.f);
      cst[r] = cn;
      float hn = so * fmaxf(cn, 0.f);

      uint32_t hb = __float_as_uint(hn);
      uint32_t hi16 = hb >> 16;
      float res = hn - __uint_as_float(hb & 0xffff0000u);
      uint32_t lo16 = __float_as_uint(res) >> 16;
      uint32_t word = hi16 | (lo16 << 16);
      if (gate == r) word_out = word;
      if (t == Tq - 1 && gate == r)
        stf_cc(hfin + (size_t)(mg * 16 + h4 * 4 + r) * Hq + unit, hn);
    }
    stg[pb][h4 * 4 + gate][wv * 4 + (c >> 2)] = word_out;

    if (t == Tq - 1) wait_vm0();   // drain hfin stores before epilogue flag
    __syncthreads();   // barrier D: stg tile complete (+ all hfin drained)

    // publish: wave 1, full lines, tag embedded, FIRE-AND-FORGET
    if (wv == 1) {
      const int pn = pb ^ 1;
      const uint32_t ntag = (((uint32_t)(t + 1) >> 1) & 1u) << 16;
      u32x4 v = *(const u32x4*)&stg[pb][l >> 2][(l & 3) * 4];
      v.x = (v.x & ~0x10000u) | ntag;
      char* sp = (char*)hbuf + (size_t)pn * 262144 +
                 (size_t)(mg * 16 + (l >> 2)) * 2048 + ng * 64 + (l & 3) * 16;
      st16_cc(sp, v);
      if (t == Tq - 1 && l == 0)   // after barrier D: every wave's hfin drained
        __hip_atomic_store(&prod[mg * 32 + ng], (uint32_t)Tq,
                           __ATOMIC_RELAXED, __HIP_MEMORY_SCOPE_AGENT);
    }
  }

  // ---------------- epilogue: y = h_last @ Wd + bd --------------------------
  if (wg < 32) {
    const int mgy = wg >> 2;
    if (tid < 32) poll1(&prod[mgy * 32 + tid], (uint32_t)Tq);
    __syncthreads();
    float* lflat = &lds[0][0];
    {
      const int r = tid >> 6, o = (tid & 63) * 8;
      const char* src = (const char*)(hfin + (size_t)(wg * 4 + r) * Hq + o);
      uint4 a, b;
      LD16(a, src, "0");
      LD16(b, src, "16");
      wait_vm0();
      *(uint4*)(lflat + r * 512 + o) = a;
      *(uint4*)(lflat + r * 512 + o + 4) = b;
    }
    __syncthreads();
    const int r = tid >> 6, j = tid & 63;
    const float* hr = lflat + r * 512;
    float acc = bd[j];
    #pragma unroll 8
    for (int k = 0; k < Hq; ++k)
      acc = fmaf(hr[k], Wd[(size_t)k * FUTq + j], acc);
    out[(wg * 4 + r) * FUTq + j] = acc;
  }
}

extern "C" void kernel_launch(void* const* d_in, const int* in_sizes, int n_in,
                              void* d_out, int out_size, void* d_ws, size_t ws_size,
                              hipStream_t stream) {
  (void)in_sizes; (void)n_in; (void)out_size; (void)ws_size;
  const float* x  = (const float*)d_in[0];
  const float* W  = (const float*)d_in[1];
  const float* U  = (const float*)d_in[2];
  const float* b  = (const float*)d_in[3];
  const float* Wd = (const float*)d_in[4];
  const float* bd = (const float*)d_in[5];

  uint32_t* hbuf = (uint32_t*)d_ws;                          // 512 KB (2 parities)
  uint32_t* prod = (uint32_t*)((char*)d_ws + 524288);        // 1 KB
  float*    hfin = (float*)((char*)d_ws + 528384);           // 256 KB

  // parity 0 = h_0 = zeros (tag bits 0 = expected tag of h_0);
  // parity 1 = 0xFF (tag bits 1 != expected tag of h_1 -> forces wait);
  // flags = 0.
  (void)hipMemsetAsync(d_ws, 0, 262144, stream);
  (void)hipMemsetAsync((char*)d_ws + 262144, 0xFF, 262144, stream);
  (void)hipMemsetAsync((char*)d_ws + 524288, 0, 1024, stream);

  hipLaunchKernelGGL(lstm_persist, dim3(256), dim3(256), 0, stream,
                     x, W, U, b, Wd, bd, hbuf, prod, hfin, (float*)d_out);
}